// Round 16
// baseline (75.828 us; speedup 1.0000x reference)
//
#include <hip/hip_runtime.h>

#define NPTS 4096
#define DIMP 17                     // DIM+1
#define ROWP 20                     // LDS tile row stride (floats)
#define RROW 21                     // reduction row stride (odd -> conflict-free)
#define JPB  256                    // j's per block (32 per wave, 8 waves)
#define NSLAB (NPTS / JPB)          // 16 j-slabs
#define NIB   (NPTS / 64)           // 64 i-columns
#define FPART (NSLAB * DIMP * NPTS) // SoA F partials: ws[slab][k][i]
#define WSE   FPART                 // E accumulator (1 float)
#define CCNT  (FPART + 1)           // colcnt[64] (int)
#define WCNT  (FPART + 65)          // winner counter (int)
#define CTRLB ((1 + NIB + 1) * 4)   // control bytes to zero per call
#define REDF  (448 * RROW)          // reduction floats (7 waves x 64 rows)

typedef float v2f __attribute__((ext_vector_type(2)));
typedef float v4f __attribute__((ext_vector_type(4)));

// Single fused kernel: grid (64, 16), block 512 = 8 waves, 4 blocks/CU.
// Pair loop identical to R14 (best measured). Epilogue: SoA partial write +
// device-fence + colcnt atomic; the 16th block of a column reduces it (all 8
// waves, coalesced), clips, stores F. 64th column-winner writes E. No spins.
__global__ __launch_bounds__(512) void hydra_pair_kernel(
    const float* __restrict__ h, float* __restrict__ ws,
    float* __restrict__ out, const int use_ws) {
    const int tid   = threadIdx.x;
    const int lane  = tid & 63;
    const int wid   = tid >> 6;                 // 0..7
    const int i     = blockIdx.x * 64 + lane;
    const int jbase = blockIdx.y * JPB;

    __shared__ __align__(16) float lds[REDF + 16];   // 37.7 KB (tile overlaps)
    __shared__ int flag;

    // coalesced stage of the 256-j tile (rows padded to ROWP)
    for (int idx = tid; idx < JPB * DIMP; idx += 512) {
        const int j = idx / DIMP;
        const int k = idx - j * DIMP;
        lds[j * ROWP + k] = h[jbase * DIMP + idx];
    }
    if (tid == 0) flag = 0;

    // metric-folded i-row, packed: nh = (t, -s) -> dot(nh, hj) = +cosh(d) = m
    v2f nhp[8];
    float nh16;
#pragma unroll
    for (int p = 0; p < 8; ++p) {
        const float s1 = (p == 0) ? 1.0f : -1.0f;
        nhp[p].x = s1 * h[i * DIMP + 2 * p];
        nhp[p].y = -h[i * DIMP + 2 * p + 1];
    }
    nh16 = -h[i * DIMP + 16];

    __syncthreads();

    v2f acp[8];
#pragma unroll
    for (int p = 0; p < 8; ++p) acp[p] = (v2f)(0.0f);
    float ac16 = 0.0f, sm = 0.0f, eacc = 0.0f;

    const float* rowp = lds + (wid * 32) * ROWP;
    for (int jj = 0; jj < 32; ++jj, rowp += ROWP) {
        const v4f a0 = ((const v4f*)rowp)[0];
        const v4f a1 = ((const v4f*)rowp)[1];
        const v4f a2 = ((const v4f*)rowp)[2];
        const v4f a3 = ((const v4f*)rowp)[3];
        const float a16 = rowp[16];

        // Lorentz dot (packed, 2 chains)
        v2f c0 = nhp[0] * a0.lo;
        v2f c1 = nhp[1] * a0.hi;
        c0 = __builtin_elementwise_fma(nhp[2], a1.lo, c0);
        c1 = __builtin_elementwise_fma(nhp[3], a1.hi, c1);
        c0 = __builtin_elementwise_fma(nhp[4], a2.lo, c0);
        c1 = __builtin_elementwise_fma(nhp[5], a2.hi, c1);
        c0 = __builtin_elementwise_fma(nhp[6], a3.lo, c0);
        c1 = __builtin_elementwise_fma(nhp[7], a3.hi, c1);
        const v2f cs = c0 + c1;
        const float m = fmaf(nh16, a16, cs.x + cs.y);        // cosh(d)

        // transform: m -> C = -dVdd * d / sinh(d); E += t - u; sm += C*m
        const float ss = fmaxf(fmaf(m, m, -1.0f), 2e-7f);    // sinh^2
        const float r  = __builtin_amdgcn_rsqf(ss);          // 1/sinh
        const float w  = ((m - 1.0f) - ss * r) + 1.0f;       // e^-d (>0 here)
        const float lg = __logf(w);                          // -d
        const float t  = __builtin_amdgcn_sqrtf(w);          // e^-d/2
        const float u  = w * w;                              // e^-2d
        const float K  = fmaf(0.5f, t, -(u + u));            // -dVdd
        const float C  = (K * r) * (-lg);                    // K*d/sinh
        eacc += (t - u);
        sm = fmaf(C, m, sm);

        const v2f Cs = {C, C};
        acp[0] = __builtin_elementwise_fma(Cs, a0.lo, acp[0]);
        acp[1] = __builtin_elementwise_fma(Cs, a0.hi, acp[1]);
        acp[2] = __builtin_elementwise_fma(Cs, a1.lo, acp[2]);
        acp[3] = __builtin_elementwise_fma(Cs, a1.hi, acp[3]);
        acp[4] = __builtin_elementwise_fma(Cs, a2.lo, acp[4]);
        acp[5] = __builtin_elementwise_fma(Cs, a2.hi, acp[5]);
        acp[6] = __builtin_elementwise_fma(Cs, a3.lo, acp[6]);
        acp[7] = __builtin_elementwise_fma(Cs, a3.hi, acp[7]);
        ac16 = fmaf(C, a16, ac16);
    }

    // F_i = ac - sm*h_i ; nh = (t, -s) so h_i[0] = nhp[0].x, h_i[k>=1] = -nh[k]
    float ac[DIMP];
    ac[0] = fmaf(-sm, nhp[0].x, acp[0].x);
    ac[1] = fmaf( sm, nhp[0].y, acp[0].y);
#pragma unroll
    for (int p = 1; p < 8; ++p) {
        ac[2 * p]     = fmaf(sm, nhp[p].x, acp[p].x);
        ac[2 * p + 1] = fmaf(sm, nhp[p].y, acp[p].y);
    }
    ac[16] = fmaf(sm, nh16, ac16);

#pragma unroll
    for (int off = 32; off > 0; off >>= 1) eacc += __shfl_xor(eacc, off);

    __syncthreads();   // tile reads done; reuse LDS for cross-wave reduction
    if (wid > 0) {
        float* dst = lds + ((wid - 1) * 64 + lane) * RROW;
#pragma unroll
        for (int k = 0; k < DIMP; ++k) dst[k] = ac[k];
        if (lane == 0) lds[REDF + wid] = eacc;
    }
    __syncthreads();

    if (wid == 0) {
        float esum = eacc;
#pragma unroll
        for (int q = 1; q < 8; ++q) esum += lds[REDF + q];
#pragma unroll
        for (int q = 0; q < 7; ++q) {
            const float* src = lds + (q * 64 + lane) * RROW;
#pragma unroll
            for (int k = 0; k < DIMP; ++k) ac[k] += src[k];
        }
        if (use_ws) {
            // SoA partial write: ws[slab][k][i], lane-consecutive per k
            float* dst = ws + (size_t)blockIdx.y * (DIMP * NPTS) + i;
#pragma unroll
            for (int k = 0; k < DIMP; ++k) dst[k * NPTS] = ac[k];
            if (lane == 0) atomicAdd(&ws[WSE], esum);
            __threadfence();   // release: partials + E visible device-wide
            if (lane == 0) {
                int* colcnt = (int*)(ws + CCNT);
                const int old = atomicAdd(&colcnt[blockIdx.x], 1);
                if (old == NSLAB - 1) flag = 1;   // we are the column's last
            }
        } else {
#pragma unroll
            for (int k = 0; k < DIMP; ++k) atomicAdd(&out[i * DIMP + k], ac[k]);
            if (lane == 0) atomicAdd(&out[NPTS * DIMP], esum);
        }
    }
    __syncthreads();

    if (use_ws && flag) {
        // Column reduction: wave w sums slabs {2w, 2w+1} (coalesced reads)
        float v[DIMP];
#pragma unroll
        for (int k = 0; k < DIMP; ++k) v[k] = 0.0f;
#pragma unroll
        for (int t2 = 0; t2 < 2; ++t2) {
            const int s = 2 * wid + t2;
            const float* base = ws + (size_t)s * (DIMP * NPTS) + i;
#pragma unroll
            for (int k = 0; k < DIMP; ++k) v[k] += base[k * NPTS];
        }
        if (wid > 0) {
            float* dst = lds + ((wid - 1) * 64 + lane) * RROW;
#pragma unroll
            for (int k = 0; k < DIMP; ++k) dst[k] = v[k];
        }
        __syncthreads();
        if (wid == 0) {
#pragma unroll
            for (int q = 0; q < 7; ++q) {
                const float* src = lds + (q * 64 + lane) * RROW;
#pragma unroll
                for (int k = 0; k < DIMP; ++k) v[k] += src[k];
            }
            float ssn = 0.0f;
#pragma unroll
            for (int k = 0; k < DIMP; ++k) ssn = fmaf(v[k], v[k], ssn);
            const float nrm   = sqrtf(ssn);
            const float scale = fminf(6.0f / fmaxf(nrm, 1e-8f), 1.0f);
#pragma unroll
            for (int k = 0; k < DIMP; ++k) out[i * DIMP + k] = v[k] * scale;
        }
        if (tid == 0) {
            int* wincnt = (int*)(ws + WCNT);
            const int old2 = atomicAdd(wincnt, 1);
            if (old2 == NIB - 1) {   // last column winner: all E-adds done
                const float E = atomicAdd(&ws[WSE], 0.0f);
                out[NPTS * DIMP] = 0.5f * E;
            }
        }
    }
}

// Fallback pass 2 (only when ws is too small): clip + E*0.5 from atomics.
__global__ __launch_bounds__(256) void hydra_finalize_kernel(
    float* __restrict__ out) {
    const int i = blockIdx.x * 256 + threadIdx.x;
    if (i < NPTS) {
        float v[DIMP];
        float ssn = 0.0f;
#pragma unroll
        for (int k = 0; k < DIMP; ++k) {
            v[k] = out[i * DIMP + k];
            ssn = fmaf(v[k], v[k], ssn);
        }
        const float nrm   = sqrtf(ssn);
        const float scale = fminf(6.0f / fmaxf(nrm, 1e-8f), 1.0f);
#pragma unroll
        for (int k = 0; k < DIMP; ++k) out[i * DIMP + k] = v[k] * scale;
    }
    if (blockIdx.x == 0 && threadIdx.x == 0) out[NPTS * DIMP] *= 0.5f;
}

extern "C" void kernel_launch(void* const* d_in, const int* in_sizes, int n_in,
                              void* d_out, int out_size, void* d_ws, size_t ws_size,
                              hipStream_t stream) {
    const float* h = (const float*)d_in[0];
    float* out = (float*)d_out;
    float* ws  = (float*)d_ws;

    const size_t need = (size_t)(FPART + 66) * sizeof(float);
    const int use_ws = (ws_size >= need) ? 1 : 0;

    if (use_ws) {
        // zero E accumulator + colcnt[64] + wincnt (268 B)
        hipMemsetAsync(ws + WSE, 0, CTRLB, stream);
    } else {
        hipMemsetAsync(d_out, 0, (size_t)out_size * sizeof(float), stream);
    }

    dim3 grid(NIB, NSLAB);
    hydra_pair_kernel<<<grid, 512, 0, stream>>>(h, ws, out, use_ws);
    if (!use_ws) {
        hydra_finalize_kernel<<<NPTS / 256, 256, 0, stream>>>(out);
    }
}

// Round 17
// 49.535 us; speedup vs baseline: 1.5308x; 1.5308x over previous
//
#include <hip/hip_runtime.h>

#define NPTS 4096
#define DIMP 17                     // DIM+1
#define RROW 21                     // reduction row stride (odd -> conflict-free)
#define JPB  256                    // j's per block (64 per wave)
#define NSLAB (NPTS / JPB)          // 16 j-slabs
#define NIB   (NPTS / 64)           // 64 i-blocks
#define EOFF  (NSLAB * DIMP * NPTS) // float offset of E partials (SoA ws)
#define NEP   (NSLAB * NIB)         // 1024 E partials
#define REDF  (192 * RROW)          // reduction floats (3 waves x 64 rows)

typedef float v4f __attribute__((ext_vector_type(4)));

// broadcast lane jj's value to all lanes via v_readlane (VALU->SGPR, no memory)
#define RL(x, l) __uint_as_float(__builtin_amdgcn_readlane(__float_as_uint(x), (l)))

// Pass 1: grid (64, 16), block 256 = 4 waves. NO LDS tile, NO staging sync:
// each lane holds one j-row in registers (lane l -> row j0+l); per iteration
// the row is broadcast with 17 v_readlane (results are wave-uniform -> SGPRs,
// feeding v_fma as the scalar operand). The inner loop has zero memory
// dependencies -> stalls are in-pipe only. Lean validated math as R12-R15.
__global__ __launch_bounds__(256) void hydra_pair_kernel(
    const float* __restrict__ h, float* __restrict__ ws,
    float* __restrict__ out, const int use_ws) {
    const int tid  = threadIdx.x;
    const int lane = tid & 63;
    const int wid  = tid >> 6;                 // 0..3
    const int i    = blockIdx.x * 64 + lane;
    const int j0   = blockIdx.y * JPB + wid * 64;

    __shared__ float lds[REDF + 16];           // reduction only (16.2 KB)

    // lane's own j-row (registers; read once, L2-resident)
    float hjr[DIMP];
#pragma unroll
    for (int k = 0; k < DIMP; ++k) hjr[k] = h[(j0 + lane) * DIMP + k];

    // metric-folded i-row: nh = (t, -s) -> dot(nh, hj) = +cosh(d) = m
    float nh[DIMP];
#pragma unroll
    for (int k = 0; k < DIMP; ++k) nh[k] = -h[i * DIMP + k];
    nh[0] = -nh[0];

    float ac[DIMP];
#pragma unroll
    for (int k = 0; k < DIMP; ++k) ac[k] = 0.0f;
    float sm = 0.0f, eacc = 0.0f;

#pragma unroll 2
    for (int jj = 0; jj < 64; ++jj) {
        // broadcast row jj of this wave's 64 rows (17 readlanes, no memory)
        float b[DIMP];
#pragma unroll
        for (int k = 0; k < DIMP; ++k) b[k] = RL(hjr[k], jj);

        // Lorentz dot, 2-way split chains
        float p0 = nh[0] * b[0], p1 = nh[1] * b[1];
#pragma unroll
        for (int k = 2; k < 16; k += 2) {
            p0 = fmaf(nh[k], b[k], p0);
            p1 = fmaf(nh[k + 1], b[k + 1], p1);
        }
        const float m = fmaf(nh[16], b[16], p0 + p1);        // cosh(d)

        // transform: m -> C = -dVdd * d / sinh(d); E += t - u; sm += C*m
        const float ss = fmaxf(fmaf(m, m, -1.0f), 2e-7f);    // sinh^2
        const float r  = __builtin_amdgcn_rsqf(ss);          // 1/sinh
        const float w  = ((m - 1.0f) - ss * r) + 1.0f;       // e^-d (>0)
        const float lg = __logf(w);                          // -d
        const float t  = __builtin_amdgcn_sqrtf(w);          // e^-d/2
        const float u  = w * w;                              // e^-2d
        const float K  = fmaf(0.5f, t, -(u + u));            // -dVdd
        const float C  = (K * r) * (-lg);                    // K*d/sinh
        eacc += (t - u);
        sm = fmaf(C, m, sm);

#pragma unroll
        for (int k = 0; k < DIMP; ++k) ac[k] = fmaf(C, b[k], ac[k]);
    }

    // F_i = ac - sm*h_i ; nh = (t, -s) so h_i[0] = nh[0], h_i[k>=1] = -nh[k]
    ac[0] = fmaf(-sm, nh[0], ac[0]);
#pragma unroll
    for (int k = 1; k < DIMP; ++k) ac[k] = fmaf(sm, nh[k], ac[k]);

#pragma unroll
    for (int off = 32; off > 0; off >>= 1) eacc += __shfl_xor(eacc, off);

    __syncthreads();
    if (wid > 0) {
        float* dst = lds + ((wid - 1) * 64 + lane) * RROW;
#pragma unroll
        for (int k = 0; k < DIMP; ++k) dst[k] = ac[k];
        if (lane == 0) lds[REDF + wid] = eacc;
    }
    __syncthreads();

    if (wid == 0) {
        const float esum = eacc + lds[REDF + 1] + lds[REDF + 2] + lds[REDF + 3];
#pragma unroll
        for (int q = 0; q < 3; ++q) {
            const float* src = lds + (q * 64 + lane) * RROW;
#pragma unroll
            for (int k = 0; k < DIMP; ++k) ac[k] += src[k];
        }
        if (use_ws) {
            // SoA: ws[slab][k][i] -> coalesced b32 stores per k
            float* dst = ws + (size_t)blockIdx.y * (DIMP * NPTS) + i;
#pragma unroll
            for (int k = 0; k < DIMP; ++k) dst[k * NPTS] = ac[k];
            if (lane == 0) ws[EOFF + blockIdx.y * NIB + blockIdx.x] = esum;
        } else {
#pragma unroll
            for (int k = 0; k < DIMP; ++k) atomicAdd(&out[i * DIMP + k], ac[k]);
            if (lane == 0) atomicAdd(&out[NPTS * DIMP], esum);
        }
    }
}

// Pass 2: grid 64 blocks x 256. lane -> i (64 per block), wid -> slab quarter.
// SoA ws: all reads are 64-lane-contiguous 256 B lines (fully coalesced).
__global__ __launch_bounds__(256) void hydra_finalize_kernel(
    const float* __restrict__ ws, float* __restrict__ out, const int use_ws) {
    const int tid  = threadIdx.x;
    const int lane = tid & 63;
    const int q    = tid >> 6;
    const int i    = blockIdx.x * 64 + lane;

    __shared__ __align__(16) float red[3 * 64 * RROW + 8];

    float v[DIMP];
#pragma unroll
    for (int k = 0; k < DIMP; ++k) v[k] = 0.0f;

    if (use_ws) {
#pragma unroll
        for (int ssl = 0; ssl < NSLAB / 4; ++ssl) {
            const int s = q * (NSLAB / 4) + ssl;
            const float* base = ws + (size_t)s * (DIMP * NPTS) + i;
#pragma unroll
            for (int k = 0; k < DIMP; ++k) v[k] += base[k * NPTS];
        }
        if (q > 0) {
            float* dst = red + ((q - 1) * 64 + lane) * RROW;
#pragma unroll
            for (int k = 0; k < DIMP; ++k) dst[k] = v[k];
        }
        __syncthreads();
        if (q == 0) {
#pragma unroll
            for (int qq = 0; qq < 3; ++qq) {
                const float* src = red + (qq * 64 + lane) * RROW;
#pragma unroll
                for (int k = 0; k < DIMP; ++k) v[k] += src[k];
            }
        }
    } else if (q == 0) {
#pragma unroll
        for (int k = 0; k < DIMP; ++k) v[k] = out[i * DIMP + k];
    }

    if (q == 0) {
        float ss = 0.0f;
#pragma unroll
        for (int k = 0; k < DIMP; ++k) ss = fmaf(v[k], v[k], ss);
        const float nrm   = sqrtf(ss);
        const float scale = fminf(6.0f / fmaxf(nrm, 1e-8f), 1.0f);
#pragma unroll
        for (int k = 0; k < DIMP; ++k) out[i * DIMP + k] = v[k] * scale;
    }

    if (blockIdx.x == 0) {
        if (use_ws) {
            float e = 0.0f;
#pragma unroll
            for (int t = 0; t < NEP / 256; ++t) e += ws[EOFF + tid + t * 256];
#pragma unroll
            for (int off = 32; off > 0; off >>= 1) e += __shfl_xor(e, off);
            __shared__ float es[4];
            if (lane == 0) es[q] = e;
            __syncthreads();
            if (tid == 0) out[NPTS * DIMP] = 0.5f * (es[0] + es[1] + es[2] + es[3]);
        } else {
            if (tid == 0) out[NPTS * DIMP] *= 0.5f;
        }
    }
}

extern "C" void kernel_launch(void* const* d_in, const int* in_sizes, int n_in,
                              void* d_out, int out_size, void* d_ws, size_t ws_size,
                              hipStream_t stream) {
    const float* h = (const float*)d_in[0];
    float* out = (float*)d_out;
    float* ws  = (float*)d_ws;

    const size_t need = (size_t)(EOFF + NEP) * sizeof(float);
    const int use_ws = (ws_size >= need) ? 1 : 0;
    if (!use_ws) {
        hipMemsetAsync(d_out, 0, (size_t)out_size * sizeof(float), stream);
    }

    dim3 grid(NIB, NSLAB);
    hydra_pair_kernel<<<grid, 256, 0, stream>>>(h, ws, out, use_ws);
    hydra_finalize_kernel<<<64, 256, 0, stream>>>(ws, out, use_ws);
}

// Round 18
// 45.430 us; speedup vs baseline: 1.6691x; 1.0904x over previous
//
#include <hip/hip_runtime.h>

#define NPTS 4096
#define DIMP 17                     // DIM+1
#define RROW 21                     // reduction row stride (odd -> conflict-free)
#define JPB  256                    // j's per block (64 per wave)
#define NSLAB (NPTS / JPB)          // 16 j-slabs
#define NIB   (NPTS / 64)           // 64 i-blocks
#define EOFF  (NSLAB * DIMP * NPTS) // float offset of E partials (SoA ws)
#define NEP   (NSLAB * NIB)         // 1024 E partials
#define REDF  (192 * RROW)          // reduction floats (3 waves x 64 rows)
#define LDS_SZ (REDF * 4 + 64)      // 16.2 KB; f16 tile (10.2 KB) overlaps

typedef float    v4f __attribute__((ext_vector_type(4)));
typedef _Float16 h2  __attribute__((ext_vector_type(2)));
typedef _Float16 h8  __attribute__((ext_vector_type(8)));

// Pass 1: grid (64, 16), block 256 = 4 waves, 1 i/lane, 64 j/wave (R12 geo).
// LDS-pipe is the measured bottleneck (~23 us/CU at 5 f32 reads/row); the
// j-tile is stored in f16 (36 B/row = 2x b128 + 1x b32 -> ~30 cyc/row) and
// consumed natively: dot = 9x v_dot2_f32_f16 (f32 accum), acc = 9x
// v_pk_fma_f16. Transform stays f32 (E precision). Validated lean math.
__global__ __launch_bounds__(256) void hydra_pair_kernel(
    const float* __restrict__ h, float* __restrict__ ws,
    float* __restrict__ out, const int use_ws) {
    const int tid   = threadIdx.x;
    const int lane  = tid & 63;
    const int wid   = tid >> 6;                 // 0..3
    const int i     = blockIdx.x * 64 + lane;
    const int jbase = blockIdx.y * JPB;

    __shared__ __align__(16) char ldsb[LDS_SZ];

    // stage f16 tile: row j = 18 halfs (elem 17 = 0 pad), stride 40 B
    h2* tile = (h2*)ldsb;
    for (int idx = tid; idx < JPB * 9; idx += 256) {
        const int j = idx / 9, e = idx - 9 * j;
        const float f0 = h[(jbase + j) * DIMP + 2 * e];
        const float f1 = (e < 8) ? h[(jbase + j) * DIMP + 2 * e + 1] : 0.0f;
        h2 v; v.x = (_Float16)f0; v.y = (_Float16)f1;
        tile[j * 10 + e] = v;
    }

    // metric-folded i-row in f16 pairs: nh = (t, -s), elem 17 = 0
    h2 nhh[9];
#pragma unroll
    for (int p = 0; p < 9; ++p) {
        const float s0 = (p == 0) ? 1.0f : -1.0f;
        const float f0 = s0 * h[i * DIMP + 2 * p];
        const float f1 = (p < 8) ? -h[i * DIMP + 2 * p + 1] : 0.0f;
        nhh[p].x = (_Float16)f0; nhh[p].y = (_Float16)f1;
    }

    __syncthreads();

    h2 accp[9];
#pragma unroll
    for (int p = 0; p < 9; ++p) accp[p] = (h2)(_Float16)0;
    float sm = 0.0f, eacc = 0.0f;

    const char* rowp = ldsb + (wid * 64) * 40;
#pragma unroll 2
    for (int jj = 0; jj < 64; ++jj, rowp += 40) {
        const h8 b0 = ((const h8*)rowp)[0];            // elems 0-7
        const h8 b1 = ((const h8*)rowp)[1];            // elems 8-15
        const h2 b2 = *(const h2*)(rowp + 32);         // elems 16,17(=0)

        // Lorentz dot: 9x v_dot2_f32_f16, two chains
        float s0 = __builtin_amdgcn_fdot2(nhh[0], b0.lo.lo, 0.0f, false);
        float s1 = __builtin_amdgcn_fdot2(nhh[1], b0.lo.hi, 0.0f, false);
        s0 = __builtin_amdgcn_fdot2(nhh[2], b0.hi.lo, s0, false);
        s1 = __builtin_amdgcn_fdot2(nhh[3], b0.hi.hi, s1, false);
        s0 = __builtin_amdgcn_fdot2(nhh[4], b1.lo.lo, s0, false);
        s1 = __builtin_amdgcn_fdot2(nhh[5], b1.lo.hi, s1, false);
        s0 = __builtin_amdgcn_fdot2(nhh[6], b1.hi.lo, s0, false);
        s1 = __builtin_amdgcn_fdot2(nhh[7], b1.hi.hi, s1, false);
        s0 = __builtin_amdgcn_fdot2(nhh[8], b2,       s0, false);
        const float m = s0 + s1;                       // cosh(d)

        // f32 transform: m -> C = -dVdd * d / sinh(d); E += t-u; sm += C*m
        const float ss = fmaxf(fmaf(m, m, -1.0f), 2e-7f);    // sinh^2
        const float r  = __builtin_amdgcn_rsqf(ss);          // 1/sinh
        const float w  = ((m - 1.0f) - ss * r) + 1.0f;       // e^-d (>0)
        const float lg = __logf(w);                          // -d
        const float t  = __builtin_amdgcn_sqrtf(w);          // e^-d/2
        const float u  = w * w;                              // e^-2d
        const float K  = fmaf(0.5f, t, -(u + u));            // -dVdd
        const float C  = (K * r) * (-lg);                    // K*d/sinh
        eacc += (t - u);
        sm = fmaf(C, m, sm);

        // f16 accumulate: 9x v_pk_fma_f16
        const _Float16 ch = (_Float16)C;
        const h2 Ch = {ch, ch};
        accp[0] = __builtin_elementwise_fma(Ch, b0.lo.lo, accp[0]);
        accp[1] = __builtin_elementwise_fma(Ch, b0.lo.hi, accp[1]);
        accp[2] = __builtin_elementwise_fma(Ch, b0.hi.lo, accp[2]);
        accp[3] = __builtin_elementwise_fma(Ch, b0.hi.hi, accp[3]);
        accp[4] = __builtin_elementwise_fma(Ch, b1.lo.lo, accp[4]);
        accp[5] = __builtin_elementwise_fma(Ch, b1.lo.hi, accp[5]);
        accp[6] = __builtin_elementwise_fma(Ch, b1.hi.lo, accp[6]);
        accp[7] = __builtin_elementwise_fma(Ch, b1.hi.hi, accp[7]);
        accp[8] = __builtin_elementwise_fma(Ch, b2,       accp[8]);
    }

    // to f32 and fold: F_i = ac - sm * h_i (h_i reloaded in f32, L2-hot)
    float ac[DIMP];
#pragma unroll
    for (int p = 0; p < 8; ++p) {
        ac[2 * p]     = (float)accp[p].x;
        ac[2 * p + 1] = (float)accp[p].y;
    }
    ac[16] = (float)accp[8].x;
#pragma unroll
    for (int k = 0; k < DIMP; ++k) ac[k] = fmaf(-sm, h[i * DIMP + k], ac[k]);

#pragma unroll
    for (int off = 32; off > 0; off >>= 1) eacc += __shfl_xor(eacc, off);

    __syncthreads();   // tile reads done; reuse LDS for f32 reduction
    float* lds = (float*)ldsb;
    if (wid > 0) {
        float* dst = lds + ((wid - 1) * 64 + lane) * RROW;
#pragma unroll
        for (int k = 0; k < DIMP; ++k) dst[k] = ac[k];
        if (lane == 0) lds[REDF + wid] = eacc;
    }
    __syncthreads();

    if (wid == 0) {
        const float esum = eacc + lds[REDF + 1] + lds[REDF + 2] + lds[REDF + 3];
#pragma unroll
        for (int q = 0; q < 3; ++q) {
            const float* src = lds + (q * 64 + lane) * RROW;
#pragma unroll
            for (int k = 0; k < DIMP; ++k) ac[k] += src[k];
        }
        if (use_ws) {
            // SoA: ws[slab][k][i] -> coalesced b32 stores per k
            float* dst = ws + (size_t)blockIdx.y * (DIMP * NPTS) + i;
#pragma unroll
            for (int k = 0; k < DIMP; ++k) dst[k * NPTS] = ac[k];
            if (lane == 0) ws[EOFF + blockIdx.y * NIB + blockIdx.x] = esum;
        } else {
#pragma unroll
            for (int k = 0; k < DIMP; ++k) atomicAdd(&out[i * DIMP + k], ac[k]);
            if (lane == 0) atomicAdd(&out[NPTS * DIMP], esum);
        }
    }
}

// Pass 2: grid 64 blocks x 256. lane -> i (64 per block), wid -> slab quarter.
__global__ __launch_bounds__(256) void hydra_finalize_kernel(
    const float* __restrict__ ws, float* __restrict__ out, const int use_ws) {
    const int tid  = threadIdx.x;
    const int lane = tid & 63;
    const int q    = tid >> 6;
    const int i    = blockIdx.x * 64 + lane;

    __shared__ __align__(16) float red[3 * 64 * RROW + 8];

    float v[DIMP];
#pragma unroll
    for (int k = 0; k < DIMP; ++k) v[k] = 0.0f;

    if (use_ws) {
#pragma unroll
        for (int ssl = 0; ssl < NSLAB / 4; ++ssl) {
            const int s = q * (NSLAB / 4) + ssl;
            const float* base = ws + (size_t)s * (DIMP * NPTS) + i;
#pragma unroll
            for (int k = 0; k < DIMP; ++k) v[k] += base[k * NPTS];
        }
        if (q > 0) {
            float* dst = red + ((q - 1) * 64 + lane) * RROW;
#pragma unroll
            for (int k = 0; k < DIMP; ++k) dst[k] = v[k];
        }
        __syncthreads();
        if (q == 0) {
#pragma unroll
            for (int qq = 0; qq < 3; ++qq) {
                const float* src = red + (qq * 64 + lane) * RROW;
#pragma unroll
                for (int k = 0; k < DIMP; ++k) v[k] += src[k];
            }
        }
    } else if (q == 0) {
#pragma unroll
        for (int k = 0; k < DIMP; ++k) v[k] = out[i * DIMP + k];
    }

    if (q == 0) {
        float ss = 0.0f;
#pragma unroll
        for (int k = 0; k < DIMP; ++k) ss = fmaf(v[k], v[k], ss);
        const float nrm   = sqrtf(ss);
        const float scale = fminf(6.0f / fmaxf(nrm, 1e-8f), 1.0f);
#pragma unroll
        for (int k = 0; k < DIMP; ++k) out[i * DIMP + k] = v[k] * scale;
    }

    if (blockIdx.x == 0) {
        if (use_ws) {
            float e = 0.0f;
#pragma unroll
            for (int t = 0; t < NEP / 256; ++t) e += ws[EOFF + tid + t * 256];
#pragma unroll
            for (int off = 32; off > 0; off >>= 1) e += __shfl_xor(e, off);
            __shared__ float es[4];
            if (lane == 0) es[q] = e;
            __syncthreads();
            if (tid == 0) out[NPTS * DIMP] = 0.5f * (es[0] + es[1] + es[2] + es[3]);
        } else {
            if (tid == 0) out[NPTS * DIMP] *= 0.5f;
        }
    }
}

extern "C" void kernel_launch(void* const* d_in, const int* in_sizes, int n_in,
                              void* d_out, int out_size, void* d_ws, size_t ws_size,
                              hipStream_t stream) {
    const float* h = (const float*)d_in[0];
    float* out = (float*)d_out;
    float* ws  = (float*)d_ws;

    const size_t need = (size_t)(EOFF + NEP) * sizeof(float);
    const int use_ws = (ws_size >= need) ? 1 : 0;
    if (!use_ws) {
        hipMemsetAsync(d_out, 0, (size_t)out_size * sizeof(float), stream);
    }

    dim3 grid(NIB, NSLAB);
    hydra_pair_kernel<<<grid, 256, 0, stream>>>(h, ws, out, use_ws);
    hydra_finalize_kernel<<<64, 256, 0, stream>>>(ws, out, use_ws);
}

// Round 20
// 37.221 us; speedup vs baseline: 2.0373x; 1.2206x over previous
//
#include <hip/hip_runtime.h>

#define NPTS 4096
#define DIMP 17                     // DIM+1
#define RROW 21                     // reduction row stride (odd -> conflict-free)
#define JPB  256                    // j's per block (64 per wave)
#define NSLAB (NPTS / JPB)          // 16 j-slabs
#define NIB   (NPTS / 64)           // 64 i-blocks
#define EOFF  (NSLAB * DIMP * NPTS) // float offset of E partials (SoA ws)
#define NEP   (NSLAB * NIB)         // 1024 E partials
#define REDF  (192 * RROW)          // reduction floats (3 waves x 64 rows)
#define TROW  48                    // f16 tile row stride BYTES (16-aligned!)
#define LDS_SZ (REDF * 4 + 64)      // 16.2 KB (f16 tile 12.3 KB overlaps)

typedef float    v4f __attribute__((ext_vector_type(4)));
typedef _Float16 h2  __attribute__((ext_vector_type(2)));
typedef _Float16 h8  __attribute__((ext_vector_type(8)));
typedef __fp16   g2  __attribute__((ext_vector_type(2)));   // builtin's type

// bitcast __fp16x2 (cvt_pkrtz result) -> {h2, unsigned}
union cvtu { g2 g; h2 h; unsigned u; };

// Pass 1: grid (64, 16), block 256 = 4 waves, 1 i/lane, 64 j/wave (R12 geo).
// LDS-pipe bound (f32: 5 reads/row ~54cyc -> ~23us/CU). f16 tile with
// 16-B-ALIGNED 48-B rows: exactly 2x ds_read_b128 + 1x ds_read_b32 per row
// (~30cyc). R18's 40-B stride broke alignment and split the loads - fixed.
// Consumption: dot = 9x v_dot2_f32_f16 (f32 accum), acc = 9x v_pk_fma_f16,
// transform f32 (validated: absmax 0.031 passes).
__global__ __launch_bounds__(256) void hydra_pair_kernel(
    const float* __restrict__ h, float* __restrict__ ws,
    float* __restrict__ out, const int use_ws) {
    const int tid   = threadIdx.x;
    const int lane  = tid & 63;
    const int wid   = tid >> 6;                 // 0..3
    const int i     = blockIdx.x * 64 + lane;
    const int jbase = blockIdx.y * JPB;

    __shared__ __align__(16) char ldsb[LDS_SZ];

    // stage f16 tile: row j at byte j*48; 9 packed h2 words (elem 17 = 0)
    unsigned* tilew = (unsigned*)ldsb;
    for (int idx = tid; idx < JPB * 9; idx += 256) {
        const int j = idx / 9, e = idx - 9 * j;
        const float f0 = h[(jbase + j) * DIMP + 2 * e];
        const float f1 = (e < 8) ? h[(jbase + j) * DIMP + 2 * e + 1] : 0.0f;
        cvtu c; c.g = __builtin_amdgcn_cvt_pkrtz(f0, f1);  // v_cvt_pkrtz_f16_f32
        tilew[j * 12 + e] = c.u;
    }

    // metric-folded i-row in f16 pairs: nh = (t, -s), elem 17 = 0
    h2 nhh[9];
#pragma unroll
    for (int p = 0; p < 9; ++p) {
        const float s0 = (p == 0) ? 1.0f : -1.0f;
        const float f0 = s0 * h[i * DIMP + 2 * p];
        const float f1 = (p < 8) ? -h[i * DIMP + 2 * p + 1] : 0.0f;
        cvtu c; c.g = __builtin_amdgcn_cvt_pkrtz(f0, f1);
        nhh[p] = c.h;
    }

    __syncthreads();

    h2 accp[9];
#pragma unroll
    for (int p = 0; p < 9; ++p) accp[p] = (h2)(_Float16)0;
    float sm = 0.0f, eacc = 0.0f;

    const char* rowp = ldsb + (wid * 64) * TROW;
#pragma unroll 2
    for (int jj = 0; jj < 64; ++jj, rowp += TROW) {
        const h8 b0 = *(const h8*)(rowp);              // elems 0-7   (b128 @0)
        const h8 b1 = *(const h8*)(rowp + 16);         // elems 8-15  (b128 @16)
        const h2 b2 = *(const h2*)(rowp + 32);         // elems 16,0  (b32  @32)

        // Lorentz dot: 9x v_dot2_f32_f16, two chains
        float s0 = __builtin_amdgcn_fdot2(nhh[0], b0.lo.lo, 0.0f, false);
        float s1 = __builtin_amdgcn_fdot2(nhh[1], b0.lo.hi, 0.0f, false);
        s0 = __builtin_amdgcn_fdot2(nhh[2], b0.hi.lo, s0, false);
        s1 = __builtin_amdgcn_fdot2(nhh[3], b0.hi.hi, s1, false);
        s0 = __builtin_amdgcn_fdot2(nhh[4], b1.lo.lo, s0, false);
        s1 = __builtin_amdgcn_fdot2(nhh[5], b1.lo.hi, s1, false);
        s0 = __builtin_amdgcn_fdot2(nhh[6], b1.hi.lo, s0, false);
        s1 = __builtin_amdgcn_fdot2(nhh[7], b1.hi.hi, s1, false);
        s0 = __builtin_amdgcn_fdot2(nhh[8], b2,       s0, false);
        const float m = s0 + s1;                       // cosh(d)

        // f32 transform: m -> C = -dVdd * d / sinh(d); E += t-u; sm += C*m
        const float ss = fmaxf(fmaf(m, m, -1.0f), 2e-7f);    // sinh^2
        const float r  = __builtin_amdgcn_rsqf(ss);          // 1/sinh
        const float w  = ((m - 1.0f) - ss * r) + 1.0f;       // e^-d (>0)
        const float lg = __logf(w);                          // -d
        const float t  = __builtin_amdgcn_sqrtf(w);          // e^-d/2
        const float u  = w * w;                              // e^-2d
        const float K  = fmaf(0.5f, t, -(u + u));            // -dVdd
        const float C  = (K * r) * (-lg);                    // K*d/sinh
        eacc += (t - u);
        sm = fmaf(C, m, sm);

        // f16 accumulate: 9x v_pk_fma_f16
        const _Float16 ch = (_Float16)C;
        const h2 Ch = {ch, ch};
        accp[0] = __builtin_elementwise_fma(Ch, b0.lo.lo, accp[0]);
        accp[1] = __builtin_elementwise_fma(Ch, b0.lo.hi, accp[1]);
        accp[2] = __builtin_elementwise_fma(Ch, b0.hi.lo, accp[2]);
        accp[3] = __builtin_elementwise_fma(Ch, b0.hi.hi, accp[3]);
        accp[4] = __builtin_elementwise_fma(Ch, b1.lo.lo, accp[4]);
        accp[5] = __builtin_elementwise_fma(Ch, b1.lo.hi, accp[5]);
        accp[6] = __builtin_elementwise_fma(Ch, b1.hi.lo, accp[6]);
        accp[7] = __builtin_elementwise_fma(Ch, b1.hi.hi, accp[7]);
        accp[8] = __builtin_elementwise_fma(Ch, b2,       accp[8]);
    }

    // to f32 and fold: F_i = ac - sm * h_i (h_i reloaded in f32, L2-hot)
    float ac[DIMP];
#pragma unroll
    for (int p = 0; p < 8; ++p) {
        ac[2 * p]     = (float)accp[p].x;
        ac[2 * p + 1] = (float)accp[p].y;
    }
    ac[16] = (float)accp[8].x;
#pragma unroll
    for (int k = 0; k < DIMP; ++k) ac[k] = fmaf(-sm, h[i * DIMP + k], ac[k]);

#pragma unroll
    for (int off = 32; off > 0; off >>= 1) eacc += __shfl_xor(eacc, off);

    __syncthreads();   // tile reads done; reuse LDS for f32 reduction
    float* lds = (float*)ldsb;
    if (wid > 0) {
        float* dst = lds + ((wid - 1) * 64 + lane) * RROW;
#pragma unroll
        for (int k = 0; k < DIMP; ++k) dst[k] = ac[k];
        if (lane == 0) lds[REDF + wid] = eacc;
    }
    __syncthreads();

    if (wid == 0) {
        const float esum = eacc + lds[REDF + 1] + lds[REDF + 2] + lds[REDF + 3];
#pragma unroll
        for (int q = 0; q < 3; ++q) {
            const float* src = lds + (q * 64 + lane) * RROW;
#pragma unroll
            for (int k = 0; k < DIMP; ++k) ac[k] += src[k];
        }
        if (use_ws) {
            // SoA: ws[slab][k][i] -> coalesced b32 stores per k
            float* dst = ws + (size_t)blockIdx.y * (DIMP * NPTS) + i;
#pragma unroll
            for (int k = 0; k < DIMP; ++k) dst[k * NPTS] = ac[k];
            if (lane == 0) ws[EOFF + blockIdx.y * NIB + blockIdx.x] = esum;
        } else {
#pragma unroll
            for (int k = 0; k < DIMP; ++k) atomicAdd(&out[i * DIMP + k], ac[k]);
            if (lane == 0) atomicAdd(&out[NPTS * DIMP], esum);
        }
    }
}

// Pass 2: grid 64 blocks x 256. lane -> i (64 per block), wid -> slab quarter.
__global__ __launch_bounds__(256) void hydra_finalize_kernel(
    const float* __restrict__ ws, float* __restrict__ out, const int use_ws) {
    const int tid  = threadIdx.x;
    const int lane = tid & 63;
    const int q    = tid >> 6;
    const int i    = blockIdx.x * 64 + lane;

    __shared__ __align__(16) float red[3 * 64 * RROW + 8];

    float v[DIMP];
#pragma unroll
    for (int k = 0; k < DIMP; ++k) v[k] = 0.0f;

    if (use_ws) {
#pragma unroll
        for (int ssl = 0; ssl < NSLAB / 4; ++ssl) {
            const int s = q * (NSLAB / 4) + ssl;
            const float* base = ws + (size_t)s * (DIMP * NPTS) + i;
#pragma unroll
            for (int k = 0; k < DIMP; ++k) v[k] += base[k * NPTS];
        }
        if (q > 0) {
            float* dst = red + ((q - 1) * 64 + lane) * RROW;
#pragma unroll
            for (int k = 0; k < DIMP; ++k) dst[k] = v[k];
        }
        __syncthreads();
        if (q == 0) {
#pragma unroll
            for (int qq = 0; qq < 3; ++qq) {
                const float* src = red + (qq * 64 + lane) * RROW;
#pragma unroll
                for (int k = 0; k < DIMP; ++k) v[k] += src[k];
            }
        }
    } else if (q == 0) {
#pragma unroll
        for (int k = 0; k < DIMP; ++k) v[k] = out[i * DIMP + k];
    }

    if (q == 0) {
        float ss = 0.0f;
#pragma unroll
        for (int k = 0; k < DIMP; ++k) ss = fmaf(v[k], v[k], ss);
        const float nrm   = sqrtf(ss);
        const float scale = fminf(6.0f / fmaxf(nrm, 1e-8f), 1.0f);
#pragma unroll
        for (int k = 0; k < DIMP; ++k) out[i * DIMP + k] = v[k] * scale;
    }

    if (blockIdx.x == 0) {
        if (use_ws) {
            float e = 0.0f;
#pragma unroll
            for (int t = 0; t < NEP / 256; ++t) e += ws[EOFF + tid + t * 256];
#pragma unroll
            for (int off = 32; off > 0; off >>= 1) e += __shfl_xor(e, off);
            __shared__ float es[4];
            if (lane == 0) es[q] = e;
            __syncthreads();
            if (tid == 0) out[NPTS * DIMP] = 0.5f * (es[0] + es[1] + es[2] + es[3]);
        } else {
            if (tid == 0) out[NPTS * DIMP] *= 0.5f;
        }
    }
}

extern "C" void kernel_launch(void* const* d_in, const int* in_sizes, int n_in,
                              void* d_out, int out_size, void* d_ws, size_t ws_size,
                              hipStream_t stream) {
    const float* h = (const float*)d_in[0];
    float* out = (float*)d_out;
    float* ws  = (float*)d_ws;

    const size_t need = (size_t)(EOFF + NEP) * sizeof(float);
    const int use_ws = (ws_size >= need) ? 1 : 0;
    if (!use_ws) {
        (void)hipMemsetAsync(d_out, 0, (size_t)out_size * sizeof(float), stream);
    }

    dim3 grid(NIB, NSLAB);
    hydra_pair_kernel<<<grid, 256, 0, stream>>>(h, ws, out, use_ws);
    hydra_finalize_kernel<<<64, 256, 0, stream>>>(ws, out, use_ws);
}

// Round 21
// 36.789 us; speedup vs baseline: 2.0611x; 1.0117x over previous
//
#include <hip/hip_runtime.h>

#define NPTS 4096
#define DIMP 17                     // DIM+1
#define ROWP 20                     // LDS tile / ws row stride (floats)
#define RROW 21                     // reduction row stride (odd -> conflict-free)
#define JPB  256                    // j's per block (32 per wave, 8 waves)
#define NSLAB (NPTS / JPB)          // 16 j-slabs
#define NIB   (NPTS / 64)           // 64 i-blocks
#define EOFF  (NSLAB * NPTS * ROWP) // float offset of E partials in ws
#define NEP   (NSLAB * NIB)         // 1024 E partials
#define REDF  (448 * RROW)          // reduction floats (7 waves x 64 rows)

typedef float v2f __attribute__((ext_vector_type(2)));
typedef float v4f __attribute__((ext_vector_type(4)));

// Session-best kernel (R14, 36.63 us): grid (64, 16), block 512 = 8 waves,
// 4 blocks/CU. Lean validated math: metric-folded i-row (dot = +cosh),
// no sigmoid / D_MIN branch / diag mask, packed dot+acc from v4f
// subregisters, f32 transform. Plateau: ~31 us pair across 7 structural
// families; residue is transform-chain latency, not any saturated pipe.
__global__ __launch_bounds__(512) void hydra_pair_kernel(
    const float* __restrict__ h, float* __restrict__ ws,
    float* __restrict__ out, const int use_ws) {
    const int tid   = threadIdx.x;
    const int lane  = tid & 63;
    const int wid   = tid >> 6;                 // 0..7
    const int i     = blockIdx.x * 64 + lane;
    const int jbase = blockIdx.y * JPB;

    __shared__ __align__(16) float lds[REDF + 16];   // 37.7 KB (tile overlaps)

    // coalesced stage of the 256-j tile (rows padded to ROWP)
    for (int idx = tid; idx < JPB * DIMP; idx += 512) {
        const int j = idx / DIMP;
        const int k = idx - j * DIMP;
        lds[j * ROWP + k] = h[jbase * DIMP + idx];
    }

    // metric-folded i-row, packed: nh = (t, -s) -> dot(nh, hj) = +cosh(d) = m
    v2f nhp[8];
    float nh16;
#pragma unroll
    for (int p = 0; p < 8; ++p) {
        const float s1 = (p == 0) ? 1.0f : -1.0f;
        nhp[p].x = s1 * h[i * DIMP + 2 * p];
        nhp[p].y = -h[i * DIMP + 2 * p + 1];
    }
    nh16 = -h[i * DIMP + 16];

    __syncthreads();

    v2f acp[8];
#pragma unroll
    for (int p = 0; p < 8; ++p) acp[p] = (v2f)(0.0f);
    float ac16 = 0.0f, sm = 0.0f, eacc = 0.0f;

    const float* rowp = lds + (wid * 32) * ROWP;
    for (int jj = 0; jj < 32; ++jj, rowp += ROWP) {
        const v4f a0 = ((const v4f*)rowp)[0];
        const v4f a1 = ((const v4f*)rowp)[1];
        const v4f a2 = ((const v4f*)rowp)[2];
        const v4f a3 = ((const v4f*)rowp)[3];
        const float a16 = rowp[16];

        // Lorentz dot (packed, 2 chains)
        v2f c0 = nhp[0] * a0.lo;
        v2f c1 = nhp[1] * a0.hi;
        c0 = __builtin_elementwise_fma(nhp[2], a1.lo, c0);
        c1 = __builtin_elementwise_fma(nhp[3], a1.hi, c1);
        c0 = __builtin_elementwise_fma(nhp[4], a2.lo, c0);
        c1 = __builtin_elementwise_fma(nhp[5], a2.hi, c1);
        c0 = __builtin_elementwise_fma(nhp[6], a3.lo, c0);
        c1 = __builtin_elementwise_fma(nhp[7], a3.hi, c1);
        const v2f cs = c0 + c1;
        const float m = fmaf(nh16, a16, cs.x + cs.y);        // cosh(d)

        // transform: m -> C = -dVdd * d / sinh(d); E += t - u; sm += C*m
        const float ss = fmaxf(fmaf(m, m, -1.0f), 2e-7f);    // sinh^2
        const float r  = __builtin_amdgcn_rsqf(ss);          // 1/sinh
        const float w  = ((m - 1.0f) - ss * r) + 1.0f;       // e^-d (>0 here)
        const float lg = __logf(w);                          // -d
        const float t  = __builtin_amdgcn_sqrtf(w);          // e^-d/2
        const float u  = w * w;                              // e^-2d
        const float K  = fmaf(0.5f, t, -(u + u));            // -dVdd
        const float C  = (K * r) * (-lg);                    // K*d/sinh
        eacc += (t - u);
        sm = fmaf(C, m, sm);

        const v2f Cs = {C, C};
        acp[0] = __builtin_elementwise_fma(Cs, a0.lo, acp[0]);
        acp[1] = __builtin_elementwise_fma(Cs, a0.hi, acp[1]);
        acp[2] = __builtin_elementwise_fma(Cs, a1.lo, acp[2]);
        acp[3] = __builtin_elementwise_fma(Cs, a1.hi, acp[3]);
        acp[4] = __builtin_elementwise_fma(Cs, a2.lo, acp[4]);
        acp[5] = __builtin_elementwise_fma(Cs, a2.hi, acp[5]);
        acp[6] = __builtin_elementwise_fma(Cs, a3.lo, acp[6]);
        acp[7] = __builtin_elementwise_fma(Cs, a3.hi, acp[7]);
        ac16 = fmaf(C, a16, ac16);
    }

    // F_i = ac - sm*h_i ; nh = (t, -s) so h_i[0] = nhp[0].x, h_i[k>=1] = -nh[k]
    float ac[DIMP];
    ac[0] = fmaf(-sm, nhp[0].x, acp[0].x);
    ac[1] = fmaf( sm, nhp[0].y, acp[0].y);
#pragma unroll
    for (int p = 1; p < 8; ++p) {
        ac[2 * p]     = fmaf(sm, nhp[p].x, acp[p].x);
        ac[2 * p + 1] = fmaf(sm, nhp[p].y, acp[p].y);
    }
    ac[16] = fmaf(sm, nh16, ac16);

#pragma unroll
    for (int off = 32; off > 0; off >>= 1) eacc += __shfl_xor(eacc, off);

    __syncthreads();   // tile reads done; reuse LDS for cross-wave reduction
    if (wid > 0) {
        float* dst = lds + ((wid - 1) * 64 + lane) * RROW;
#pragma unroll
        for (int k = 0; k < DIMP; ++k) dst[k] = ac[k];
        if (lane == 0) lds[REDF + wid] = eacc;
    }
    __syncthreads();

    if (wid == 0) {
        float esum = eacc;
#pragma unroll
        for (int q = 1; q < 8; ++q) esum += lds[REDF + q];
#pragma unroll
        for (int q = 0; q < 7; ++q) {
            const float* src = lds + (q * 64 + lane) * RROW;
#pragma unroll
            for (int k = 0; k < DIMP; ++k) ac[k] += src[k];
        }
        if (use_ws) {
            float* dst = ws + ((size_t)blockIdx.y * NPTS + i) * ROWP;
#pragma unroll
            for (int k = 0; k < DIMP; ++k) dst[k] = ac[k];
            if (lane == 0) ws[EOFF + blockIdx.y * NIB + blockIdx.x] = esum;
        } else {
#pragma unroll
            for (int k = 0; k < DIMP; ++k) atomicAdd(&out[i * DIMP + k], ac[k]);
            if (lane == 0) atomicAdd(&out[NPTS * DIMP], esum);
        }
    }
}

// Pass 2: grid 64 blocks x 256. lane -> i (64 per block), wid -> slab quarter.
__global__ __launch_bounds__(256) void hydra_finalize_kernel(
    const float* __restrict__ ws, float* __restrict__ out, const int use_ws) {
    const int tid  = threadIdx.x;
    const int lane = tid & 63;
    const int q    = tid >> 6;
    const int i    = blockIdx.x * 64 + lane;

    __shared__ __align__(16) float red[3 * 64 * RROW + 8];

    float v[DIMP];
#pragma unroll
    for (int k = 0; k < DIMP; ++k) v[k] = 0.0f;

    if (use_ws) {
#pragma unroll
        for (int ssl = 0; ssl < NSLAB / 4; ++ssl) {
            const int s = q * (NSLAB / 4) + ssl;
            const float* row = ws + ((size_t)s * NPTS + i) * ROWP;
            const v4f b0 = ((const v4f*)row)[0];
            const v4f b1 = ((const v4f*)row)[1];
            const v4f b2 = ((const v4f*)row)[2];
            const v4f b3 = ((const v4f*)row)[3];
            v[0]  += b0.x; v[1]  += b0.y; v[2]  += b0.z; v[3]  += b0.w;
            v[4]  += b1.x; v[5]  += b1.y; v[6]  += b1.z; v[7]  += b1.w;
            v[8]  += b2.x; v[9]  += b2.y; v[10] += b2.z; v[11] += b2.w;
            v[12] += b3.x; v[13] += b3.y; v[14] += b3.z; v[15] += b3.w;
            v[16] += row[16];
        }
        if (q > 0) {
            float* dst = red + ((q - 1) * 64 + lane) * RROW;
#pragma unroll
            for (int k = 0; k < DIMP; ++k) dst[k] = v[k];
        }
        __syncthreads();
        if (q == 0) {
#pragma unroll
            for (int qq = 0; qq < 3; ++qq) {
                const float* src = red + (qq * 64 + lane) * RROW;
#pragma unroll
                for (int k = 0; k < DIMP; ++k) v[k] += src[k];
            }
        }
    } else if (q == 0) {
#pragma unroll
        for (int k = 0; k < DIMP; ++k) v[k] = out[i * DIMP + k];
    }

    if (q == 0) {
        float ss = 0.0f;
#pragma unroll
        for (int k = 0; k < DIMP; ++k) ss = fmaf(v[k], v[k], ss);
        const float nrm   = sqrtf(ss);
        const float scale = fminf(6.0f / fmaxf(nrm, 1e-8f), 1.0f);
#pragma unroll
        for (int k = 0; k < DIMP; ++k) out[i * DIMP + k] = v[k] * scale;
    }

    if (blockIdx.x == 0) {
        if (use_ws) {
            float e = 0.0f;
#pragma unroll
            for (int t = 0; t < NEP / 256; ++t) e += ws[EOFF + tid + t * 256];
#pragma unroll
            for (int off = 32; off > 0; off >>= 1) e += __shfl_xor(e, off);
            __shared__ float es[4];
            if (lane == 0) es[q] = e;
            __syncthreads();
            if (tid == 0) out[NPTS * DIMP] = 0.5f * (es[0] + es[1] + es[2] + es[3]);
        } else {
            if (tid == 0) out[NPTS * DIMP] *= 0.5f;
        }
    }
}

extern "C" void kernel_launch(void* const* d_in, const int* in_sizes, int n_in,
                              void* d_out, int out_size, void* d_ws, size_t ws_size,
                              hipStream_t stream) {
    const float* h = (const float*)d_in[0];
    float* out = (float*)d_out;
    float* ws  = (float*)d_ws;

    const size_t need = (size_t)(EOFF + NEP) * sizeof(float);
    const int use_ws = (ws_size >= need) ? 1 : 0;
    if (!use_ws) {
        (void)hipMemsetAsync(d_out, 0, (size_t)out_size * sizeof(float), stream);
    }

    dim3 grid(NIB, NSLAB);
    hydra_pair_kernel<<<grid, 512, 0, stream>>>(h, ws, out, use_ws);
    hydra_finalize_kernel<<<64, 256, 0, stream>>>(ws, out, use_ws);
}